// Round 1
// baseline (251.857 us; speedup 1.0000x reference)
//
#include <hip/hip_runtime.h>
#include <hip/hip_bf16.h>
#include <cstdint>

typedef unsigned short ushort_t;
typedef __bf16 bf16x8 __attribute__((ext_vector_type(8)));
typedef float f32x4 __attribute__((ext_vector_type(4)));

#define B_   16
#define S_   512
#define D_   768
#define E_   128
#define R_   2048
#define H_   768
#define H2_  384
#define K1_  1536
#define BE_  2048
#define NREL 32768

__device__ inline ushort_t f2b(float f) {
    uint32_t u = __builtin_bit_cast(uint32_t, f);
    uint32_t r = (u + 0x7fffu + ((u >> 16) & 1u)) >> 16;   // RNE
    return (ushort_t)r;
}
__device__ inline float b2f(ushort_t u) {
    uint32_t v = ((uint32_t)u) << 16;
    return __builtin_bit_cast(float, v);
}
__device__ inline float bl(uint32_t u) {
    uint32_t v = u << 16;
    return __builtin_bit_cast(float, v);
}
__device__ inline float bh(uint32_t u) {
    uint32_t v = u & 0xffff0000u;
    return __builtin_bit_cast(float, v);
}

// ---------------------------------------------------------------------------
// Prep: gather entity reps (bf16), transpose+convert weights to B^T bf16,
// build Bmat for bilinear+head-linear, zero the loss slot.
// ---------------------------------------------------------------------------
__global__ __launch_bounds__(256) void prep_kernel(
    const float* __restrict__ hidden, const float* __restrict__ emb,
    const float* __restrict__ hW1, const float* __restrict__ tW1,
    const float* __restrict__ hW2, const float* __restrict__ tW2,
    const float* __restrict__ bil, const float* __restrict__ lW,
    const int* __restrict__ ent_start, const int* __restrict__ ent_label,
    ushort_t* __restrict__ repE, ushort_t* __restrict__ hW1T, ushort_t* __restrict__ tW1T,
    ushort_t* __restrict__ hW2T, ushort_t* __restrict__ tW2T,
    ushort_t* __restrict__ BmatT, ushort_t* __restrict__ lWtT, float* __restrict__ out)
{
    int idx = blockIdx.x * 256 + threadIdx.x;
    if (idx == 0) out[0] = 0.0f;
    int i = idx;
    if (i < 3145728) {                       // repE [2048,1536]
        int row = i / 1536, c = i - row * 1536;
        int b = row >> 7;
        int st = ent_start[row], lab = ent_label[row];
        float v = (c < 768) ? hidden[((size_t)b * S_ + st) * D_ + c]
                            : emb[lab * D_ + (c - 768)];
        repE[i] = f2b(v);
        return;
    }
    i -= 3145728;
    if (i < 1179648) {                       // hW1T [768,1536]
        int n = i / 1536, k = i - n * 1536;
        hW1T[i] = f2b(hW1[(size_t)k * 768 + n]);
        return;
    }
    i -= 1179648;
    if (i < 1179648) {                       // tW1T
        int n = i / 1536, k = i - n * 1536;
        tW1T[i] = f2b(tW1[(size_t)k * 768 + n]);
        return;
    }
    i -= 1179648;
    if (i < 294912) {                        // hW2T [384,768]
        int n = i / 768, k = i - n * 768;
        hW2T[i] = f2b(hW2[(size_t)k * 384 + n]);
        return;
    }
    i -= 294912;
    if (i < 294912) {                        // tW2T
        int n = i / 768, k = i - n * 768;
        tW2T[i] = f2b(tW2[(size_t)k * 384 + n]);
        return;
    }
    i -= 294912;
    if (i < 295680) {                        // BmatT [770,384]
        int n = i / 384, kk = i - n * 384;   // kk = heads index i
        float v;
        if (n < 768) {
            int o = (n >= 384) ? 1 : 0;
            int j = n - o * 384;
            v = bil[(size_t)o * 147456 + (size_t)kk * 384 + j];
        } else {
            v = lW[kk * 2 + (n - 768)];      // head half of linear
        }
        BmatT[i] = f2b(v);
        return;
    }
    i -= 295680;
    if (i < 768) {                           // lWtT [2,384]  (tail half of linear)
        int o = i / 384, ii = i - o * 384;
        lWtT[i] = f2b(lW[(384 + ii) * 2 + o]);
    }
}

// ---------------------------------------------------------------------------
// Generic bf16 MFMA GEMM: out = relu?(A @ B^T^T + bias), A [M,K] row-major,
// Bt [N,K] row-major (i.e. B K-contiguous). blockIdx.z selects operand set.
// Block = 256 threads (4 waves), block tile 64x64, wave tile 32x32.
// ---------------------------------------------------------------------------
__global__ __launch_bounds__(256) void gemm_bt(
    const ushort_t* __restrict__ A0, const ushort_t* __restrict__ A1,
    const ushort_t* __restrict__ Bt0, const ushort_t* __restrict__ Bt1,
    const float* __restrict__ bias0, const float* __restrict__ bias1,
    ushort_t* __restrict__ out0, ushort_t* __restrict__ out1,
    int M, int N, int K, int doRelu)
{
    const ushort_t* A   = blockIdx.z ? A1 : A0;
    const ushort_t* Bt  = blockIdx.z ? Bt1 : Bt0;
    const float*   bias = blockIdx.z ? bias1 : bias0;
    ushort_t*      out  = blockIdx.z ? out1 : out0;

    int lane = threadIdx.x & 63, wave = threadIdx.x >> 6;
    int tileM = blockIdx.x * 64, tileN = blockIdx.y * 64;
    int wm = (wave >> 1) * 32, wn = (wave & 1) * 32;
    int l15 = lane & 15, quad = lane >> 4, kq = quad * 8;

    int m0 = tileM + wm + l15;
    int n0 = tileN + wn + l15;
    bool bv0 = (n0 < N), bv1 = (n0 + 16 < N);

    bf16x8 zfrag;
#pragma unroll
    for (int z = 0; z < 8; ++z) zfrag[z] = (__bf16)0.0f;

    f32x4 acc[2][2];
#pragma unroll
    for (int a = 0; a < 2; ++a)
#pragma unroll
        for (int b = 0; b < 2; ++b) {
            acc[a][b][0] = 0.f; acc[a][b][1] = 0.f;
            acc[a][b][2] = 0.f; acc[a][b][3] = 0.f;
        }

    for (int k0 = 0; k0 < K; k0 += 32) {
        bf16x8 a0 = *reinterpret_cast<const bf16x8*>(A + (size_t)m0 * K + k0 + kq);
        bf16x8 a1 = *reinterpret_cast<const bf16x8*>(A + (size_t)(m0 + 16) * K + k0 + kq);
        bf16x8 b0 = bv0 ? *reinterpret_cast<const bf16x8*>(Bt + (size_t)n0 * K + k0 + kq) : zfrag;
        bf16x8 b1 = bv1 ? *reinterpret_cast<const bf16x8*>(Bt + (size_t)(n0 + 16) * K + k0 + kq) : zfrag;
        acc[0][0] = __builtin_amdgcn_mfma_f32_16x16x32_bf16(a0, b0, acc[0][0], 0, 0, 0);
        acc[0][1] = __builtin_amdgcn_mfma_f32_16x16x32_bf16(a0, b1, acc[0][1], 0, 0, 0);
        acc[1][0] = __builtin_amdgcn_mfma_f32_16x16x32_bf16(a1, b0, acc[1][0], 0, 0, 0);
        acc[1][1] = __builtin_amdgcn_mfma_f32_16x16x32_bf16(a1, b1, acc[1][1], 0, 0, 0);
    }

#pragma unroll
    for (int mi = 0; mi < 2; ++mi) {
#pragma unroll
        for (int ni = 0; ni < 2; ++ni) {
            int gr = tileM + wm + mi * 16 + quad * 4;
            int gc = tileN + wn + ni * 16 + l15;
            if (gc < N) {
                float bb = bias ? bias[gc] : 0.0f;
#pragma unroll
                for (int r = 0; r < 4; ++r) {
                    float v = acc[mi][ni][r] + bb;
                    if (doRelu) v = fmaxf(v, 0.0f);
                    out[(size_t)(gr + r) * N + gc] = f2b(v);
                }
            }
        }
    }
}

// ---------------------------------------------------------------------------
// Per-relation: logits + log-softmax + loss. One wave per relation (x8 each).
// ---------------------------------------------------------------------------
__global__ __launch_bounds__(256) void rel_kernel(
    const ushort_t* __restrict__ Uext, const ushort_t* __restrict__ tailsE,
    const ushort_t* __restrict__ lWtT, const float* __restrict__ lb,
    const int* __restrict__ rel_head, const int* __restrict__ rel_tail,
    const int* __restrict__ rel_label, float* __restrict__ out)
{
    __shared__ float wsum[4];
    int lane = threadIdx.x & 63, wave = threadIdx.x >> 6;
    const uint32_t* lw32 = reinterpret_cast<const uint32_t*>(lWtT);
    float lb0 = lb[0], lb1 = lb[1];
    float lossAcc = 0.0f;
    int base = (blockIdx.x * 4 + wave) * 8;

    for (int q = 0; q < 8; ++q) {
        int rel = base + q;
        int b = rel >> 11;                    // R = 2048
        int h = rel_head[rel], t = rel_tail[rel], lab = rel_label[rel];
        const uint32_t* uh = reinterpret_cast<const uint32_t*>(Uext + (size_t)(b * E_ + h) * 770);
        const uint32_t* tv = reinterpret_cast<const uint32_t*>(tailsE + (size_t)(b * E_ + t) * 384);

        float a0 = 0.f, a1 = 0.f, w0s = 0.f, w1s = 0.f;
#pragma unroll
        for (int j = 0; j < 3; ++j) {
            int i = lane + 64 * j;
            uint32_t tu = tv[i];
            uint32_t u0 = uh[i], u1 = uh[192 + i];
            uint32_t q0 = lw32[i], q1 = lw32[192 + i];
            float tl = bl(tu), th = bh(tu);
            a0  += tl * bl(u0) + th * bh(u0);
            a1  += tl * bl(u1) + th * bh(u1);
            w0s += tl * bl(q0) + th * bh(q0);
            w1s += tl * bl(q1) + th * bh(q1);
        }
#pragma unroll
        for (int d = 1; d < 64; d <<= 1) {
            a0  += __shfl_xor(a0, d);
            a1  += __shfl_xor(a1, d);
            w0s += __shfl_xor(w0s, d);
            w1s += __shfl_xor(w1s, d);
        }
        const ushort_t* uhs = reinterpret_cast<const ushort_t*>(uh);
        float l0v = a0 + w0s + b2f(uhs[768]) + lb0;
        float l1v = a1 + w1s + b2f(uhs[769]) + lb1;
        if (lane == 0) {
            out[1 + 2 * rel]     = l0v;
            out[1 + 2 * rel + 1] = l1v;
        }
        float m = fmaxf(l0v, l1v);
        float lse = m + logf(expf(l0v - m) + expf(l1v - m));
        lossAcc += lse - (lab ? l1v : l0v);
    }
    if (lane == 0) wsum[wave] = lossAcc;
    __syncthreads();
    if (threadIdx.x == 0) {
        float s = wsum[0] + wsum[1] + wsum[2] + wsum[3];
        atomicAdd(out, s * (1.0f / 32768.0f));
    }
}

// ---------------------------------------------------------------------------
extern "C" void kernel_launch(void* const* d_in, const int* in_sizes, int n_in,
                              void* d_out, int out_size, void* d_ws, size_t ws_size,
                              hipStream_t stream)
{
    const float* hidden = (const float*)d_in[0];
    const float* emb    = (const float*)d_in[1];
    const float* hW1    = (const float*)d_in[2];
    const float* hb1    = (const float*)d_in[3];
    const float* hW2    = (const float*)d_in[4];
    const float* hb2    = (const float*)d_in[5];
    const float* tW1    = (const float*)d_in[6];
    const float* tb1    = (const float*)d_in[7];
    const float* tW2    = (const float*)d_in[8];
    const float* tb2    = (const float*)d_in[9];
    const float* bil    = (const float*)d_in[10];
    const float* lW     = (const float*)d_in[11];
    const float* lb     = (const float*)d_in[12];
    const int* ent_start = (const int*)d_in[13];
    const int* ent_label = (const int*)d_in[14];
    const int* rel_head  = (const int*)d_in[15];
    const int* rel_tail  = (const int*)d_in[16];
    const int* rel_label = (const int*)d_in[17];
    float* out = (float*)d_out;

    char* ws = (char*)d_ws;
    ushort_t* repE   = (ushort_t*)(ws + 0);         // [2048,1536]
    ushort_t* hW1T   = (ushort_t*)(ws + 6291456);   // [768,1536]
    ushort_t* tW1T   = (ushort_t*)(ws + 8650752);   // [768,1536]
    ushort_t* hW2T   = (ushort_t*)(ws + 11010048);  // [384,768]
    ushort_t* tW2T   = (ushort_t*)(ws + 11599872);  // [384,768]
    ushort_t* BmatT  = (ushort_t*)(ws + 12189696);  // [770,384]
    ushort_t* lWtT   = (ushort_t*)(ws + 12781056);  // [2,384]
    ushort_t* h1     = (ushort_t*)(ws + 12782592);  // [2048,768]
    ushort_t* t1     = (ushort_t*)(ws + 15928320);  // [2048,768]
    ushort_t* headsE = (ushort_t*)(ws + 19074048);  // [2048,384]
    ushort_t* tailsE = (ushort_t*)(ws + 20646912);  // [2048,384]
    ushort_t* Uext   = (ushort_t*)(ws + 22219776);  // [2048,770]

    prep_kernel<<<24966, 256, 0, stream>>>(
        hidden, emb, hW1, tW1, hW2, tW2, bil, lW, ent_start, ent_label,
        repE, hW1T, tW1T, hW2T, tW2T, BmatT, lWtT, out);

    gemm_bt<<<dim3(32, 12, 2), 256, 0, stream>>>(
        repE, repE, hW1T, tW1T, hb1, tb1, h1, t1, 2048, 768, 1536, 1);

    gemm_bt<<<dim3(32, 6, 2), 256, 0, stream>>>(
        h1, t1, hW2T, tW2T, hb2, tb2, headsE, tailsE, 2048, 384, 768, 1);

    gemm_bt<<<dim3(32, 13, 1), 256, 0, stream>>>(
        headsE, headsE, BmatT, BmatT, nullptr, nullptr, Uext, Uext, 2048, 770, 384, 0);

    rel_kernel<<<1024, 256, 0, stream>>>(
        Uext, tailsE, lWtT, lb, rel_head, rel_tail, rel_label, out);
}

// Round 2
// 209.539 us; speedup vs baseline: 1.2020x; 1.2020x over previous
//
#include <hip/hip_runtime.h>
#include <hip/hip_bf16.h>
#include <cstdint>

typedef unsigned short ushort_t;
typedef __bf16 bf16x8 __attribute__((ext_vector_type(8)));
typedef float f32x4 __attribute__((ext_vector_type(4)));

#define B_   16
#define S_   512
#define D_   768
#define E_   128
#define R_   2048
#define NREL 32768

__device__ inline ushort_t f2b(float f) {
    uint32_t u = __builtin_bit_cast(uint32_t, f);
    uint32_t r = (u + 0x7fffu + ((u >> 16) & 1u)) >> 16;   // RNE
    return (ushort_t)r;
}
__device__ inline float b2f(ushort_t u) {
    uint32_t v = ((uint32_t)u) << 16;
    return __builtin_bit_cast(float, v);
}
__device__ inline float bl(uint32_t u) {
    uint32_t v = u << 16;
    return __builtin_bit_cast(float, v);
}
__device__ inline float bh(uint32_t u) {
    uint32_t v = u & 0xffff0000u;
    return __builtin_bit_cast(float, v);
}

// ---------------------------------------------------------------------------
// Prep: coalesced float4 gather of entity reps -> bf16, plus tiny tails
// (BmatT rows 768/769 from lW-head, lWtT, loss-slot zero).
// ---------------------------------------------------------------------------
__global__ __launch_bounds__(256) void prep_kernel(
    const float* __restrict__ hidden, const float* __restrict__ emb,
    const float* __restrict__ lW,
    const int* __restrict__ ent_start, const int* __restrict__ ent_label,
    ushort_t* __restrict__ repE, ushort_t* __restrict__ BmatT,
    ushort_t* __restrict__ lWtT, float* __restrict__ out)
{
    int idx = blockIdx.x * 256 + threadIdx.x;
    if (idx == 0) out[0] = 0.0f;
    if (idx < 786432) {                      // repE [2048,1536] via float4
        int row = idx / 384, q = idx - row * 384;
        int c = q * 4;
        int b = row >> 7;
        int st = ent_start[row], lab = ent_label[row];
        const float* srcp = (c < 768)
            ? hidden + ((size_t)(b * S_ + st) * D_ + c)
            : emb + ((size_t)lab * D_ + (c - 768));
        float4 v = *reinterpret_cast<const float4*>(srcp);
        uint32_t lo = (uint32_t)f2b(v.x) | ((uint32_t)f2b(v.y) << 16);
        uint32_t hi = (uint32_t)f2b(v.z) | ((uint32_t)f2b(v.w) << 16);
        uint2 pk; pk.x = lo; pk.y = hi;
        *reinterpret_cast<uint2*>(repE + (size_t)idx * 4) = pk;
        return;
    }
    int i2 = idx - 786432;
    if (i2 < 768) {                          // BmatT rows 768/769 (head-linear)
        int o = i2 / 384, kk = i2 - o * 384;
        BmatT[(768 + o) * 384 + kk] = f2b(lW[kk * 2 + o]);
        return;
    }
    i2 -= 768;
    if (i2 < 768) {                          // lWtT [2,384] (tail-linear)
        int o = i2 / 384, ii = i2 - o * 384;
        lWtT[o * 384 + ii] = f2b(lW[(384 + ii) * 2 + o]);
    }
}

// ---------------------------------------------------------------------------
// Coalesced 32x32 LDS-tile transpose fp32 -> bf16, z selects matrix.
// ---------------------------------------------------------------------------
__global__ __launch_bounds__(256) void transpose_w(
    const float* __restrict__ hW1, const float* __restrict__ tW1,
    const float* __restrict__ hW2, const float* __restrict__ tW2,
    const float* __restrict__ bil,
    ushort_t* __restrict__ hW1T, ushort_t* __restrict__ tW1T,
    ushort_t* __restrict__ hW2T, ushort_t* __restrict__ tW2T,
    ushort_t* __restrict__ BmatT)
{
    __shared__ float tile[32][33];
    int z = blockIdx.z;
    const float* src; ushort_t* dst; int Rr, Cc;
    switch (z) {
        case 0:  src = hW1;          dst = hW1T;           Rr = 1536; Cc = 768; break;
        case 1:  src = tW1;          dst = tW1T;           Rr = 1536; Cc = 768; break;
        case 2:  src = hW2;          dst = hW2T;           Rr = 768;  Cc = 384; break;
        case 3:  src = tW2;          dst = tW2T;           Rr = 768;  Cc = 384; break;
        case 4:  src = bil;          dst = BmatT;          Rr = 384;  Cc = 384; break;
        default: src = bil + 147456; dst = BmatT + 147456; Rr = 384;  Cc = 384; break;
    }
    int tR = blockIdx.x * 32, tC = blockIdx.y * 32;
    if (tR >= Rr || tC >= Cc) return;
    int tx = threadIdx.x & 31, ty = threadIdx.x >> 5;     // ty in [0,8)
#pragma unroll
    for (int r = 0; r < 4; ++r)
        tile[ty + r * 8][tx] = src[(size_t)(tR + ty + r * 8) * Cc + tC + tx];
    __syncthreads();
#pragma unroll
    for (int r = 0; r < 4; ++r)
        dst[(size_t)(tC + ty + r * 8) * Rr + tR + tx] = f2b(tile[tx][ty + r * 8]);
}

// ---------------------------------------------------------------------------
// LDS-staged bf16 MFMA GEMM (m97 structure): out = relu?(A @ Bt^T + bias).
// A [M,K] row-major, Bt [N,K] row-major (K-contiguous). Block tile 128x128,
// 4 waves each computing 64x64. Staging via global_load_lds width 16.
// blockIdx.z selects operand set (two towers in one launch).
// ---------------------------------------------------------------------------
__global__ __launch_bounds__(256) void gemm_lds(
    const ushort_t* __restrict__ A0, const ushort_t* __restrict__ A1,
    const ushort_t* __restrict__ Bt0, const ushort_t* __restrict__ Bt1,
    const float* __restrict__ bias0, const float* __restrict__ bias1,
    ushort_t* __restrict__ out0, ushort_t* __restrict__ out1,
    int M, int N, int K, int doRelu)
{
    __shared__ ushort_t As[128 * 32];
    __shared__ ushort_t Bs[128 * 32];
    const ushort_t* A   = blockIdx.z ? A1 : A0;
    const ushort_t* Bt  = blockIdx.z ? Bt1 : Bt0;
    const float*   bias = blockIdx.z ? bias1 : bias0;
    ushort_t*      out  = blockIdx.z ? out1 : out0;

    int t = threadIdx.x;
    int lane = t & 63, wave = t >> 6;
    int tileM = blockIdx.x * 128, tileN = blockIdx.y * 128;
    int wm = (wave >> 1) * 64, wn = (wave & 1) * 64;
    int l15 = lane & 15, quad = lane >> 4;

    const ushort_t* gA = A  + (size_t)tileM * K;
    const ushort_t* gB = Bt + (size_t)tileN * K;

    f32x4 acc[4][4];
#pragma unroll
    for (int a = 0; a < 4; ++a)
#pragma unroll
        for (int b = 0; b < 4; ++b) {
            acc[a][b][0] = 0.f; acc[a][b][1] = 0.f;
            acc[a][b][2] = 0.f; acc[a][b][3] = 0.f;
        }

    for (int k0 = 0; k0 < K; k0 += 32) {
#pragma unroll
        for (int i = 0; i < 2; ++i) {
            int seg = i * 256 + t;
            int row = seg >> 2, c8 = (seg & 3) << 3;
            __builtin_amdgcn_global_load_lds(
                (const __attribute__((address_space(1))) void*)(gA + (size_t)row * K + k0 + c8),
                (__attribute__((address_space(3))) void*)(As + seg * 8), 16, 0, 0);
        }
#pragma unroll
        for (int i = 0; i < 2; ++i) {
            int seg = i * 256 + t;
            int row = seg >> 2, c8 = (seg & 3) << 3;
            __builtin_amdgcn_global_load_lds(
                (const __attribute__((address_space(1))) void*)(gB + (size_t)row * K + k0 + c8),
                (__attribute__((address_space(3))) void*)(Bs + seg * 8), 16, 0, 0);
        }
        __syncthreads();
        bf16x8 af[4], bfr[4];
#pragma unroll
        for (int mi = 0; mi < 4; ++mi)
            af[mi] = *reinterpret_cast<const bf16x8*>(As + (wm + mi * 16 + l15) * 32 + quad * 8);
#pragma unroll
        for (int ni = 0; ni < 4; ++ni)
            bfr[ni] = *reinterpret_cast<const bf16x8*>(Bs + (wn + ni * 16 + l15) * 32 + quad * 8);
#pragma unroll
        for (int mi = 0; mi < 4; ++mi)
#pragma unroll
            for (int ni = 0; ni < 4; ++ni)
                acc[mi][ni] = __builtin_amdgcn_mfma_f32_16x16x32_bf16(af[mi], bfr[ni], acc[mi][ni], 0, 0, 0);
        __syncthreads();
    }

#pragma unroll
    for (int mi = 0; mi < 4; ++mi) {
        int gr = tileM + wm + mi * 16 + quad * 4;
#pragma unroll
        for (int ni = 0; ni < 4; ++ni) {
            int gc = tileN + wn + ni * 16 + l15;
            if (gc < N) {
                float bb = bias ? bias[gc] : 0.0f;
#pragma unroll
                for (int r = 0; r < 4; ++r) {
                    float v = acc[mi][ni][r] + bb;
                    if (doRelu) v = fmaxf(v, 0.0f);
                    out[(size_t)(gr + r) * N + gc] = f2b(v);
                }
            }
        }
    }
}

// ---------------------------------------------------------------------------
// Per-relation: logits + log-softmax + loss. One wave per 8 relations.
// ---------------------------------------------------------------------------
__global__ __launch_bounds__(256) void rel_kernel(
    const ushort_t* __restrict__ Uext, const ushort_t* __restrict__ tailsE,
    const ushort_t* __restrict__ lWtT, const float* __restrict__ lb,
    const int* __restrict__ rel_head, const int* __restrict__ rel_tail,
    const int* __restrict__ rel_label, float* __restrict__ out)
{
    __shared__ float wsum[4];
    int lane = threadIdx.x & 63, wave = threadIdx.x >> 6;
    const uint32_t* lw32 = reinterpret_cast<const uint32_t*>(lWtT);
    float lb0 = lb[0], lb1 = lb[1];
    float lossAcc = 0.0f;
    int base = (blockIdx.x * 4 + wave) * 8;

    for (int q = 0; q < 8; ++q) {
        int rel = base + q;
        int b = rel >> 11;                    // R = 2048
        int h = rel_head[rel], t = rel_tail[rel], lab = rel_label[rel];
        const uint32_t* uh = reinterpret_cast<const uint32_t*>(Uext + (size_t)(b * E_ + h) * 770);
        const uint32_t* tv = reinterpret_cast<const uint32_t*>(tailsE + (size_t)(b * E_ + t) * 384);

        float a0 = 0.f, a1 = 0.f, w0s = 0.f, w1s = 0.f;
#pragma unroll
        for (int j = 0; j < 3; ++j) {
            int i = lane + 64 * j;
            uint32_t tu = tv[i];
            uint32_t u0 = uh[i], u1 = uh[192 + i];
            uint32_t q0 = lw32[i], q1 = lw32[192 + i];
            float tl = bl(tu), th = bh(tu);
            a0  += tl * bl(u0) + th * bh(u0);
            a1  += tl * bl(u1) + th * bh(u1);
            w0s += tl * bl(q0) + th * bh(q0);
            w1s += tl * bl(q1) + th * bh(q1);
        }
#pragma unroll
        for (int d = 1; d < 64; d <<= 1) {
            a0  += __shfl_xor(a0, d);
            a1  += __shfl_xor(a1, d);
            w0s += __shfl_xor(w0s, d);
            w1s += __shfl_xor(w1s, d);
        }
        const ushort_t* uhs = reinterpret_cast<const ushort_t*>(uh);
        float l0v = a0 + w0s + b2f(uhs[768]) + lb0;
        float l1v = a1 + w1s + b2f(uhs[769]) + lb1;
        if (lane == 0) {
            out[1 + 2 * rel]     = l0v;
            out[1 + 2 * rel + 1] = l1v;
        }
        float m = fmaxf(l0v, l1v);
        float lse = m + logf(expf(l0v - m) + expf(l1v - m));
        lossAcc += lse - (lab ? l1v : l0v);
    }
    if (lane == 0) wsum[wave] = lossAcc;
    __syncthreads();
    if (threadIdx.x == 0) {
        float s = wsum[0] + wsum[1] + wsum[2] + wsum[3];
        atomicAdd(out, s * (1.0f / 32768.0f));
    }
}

// ---------------------------------------------------------------------------
extern "C" void kernel_launch(void* const* d_in, const int* in_sizes, int n_in,
                              void* d_out, int out_size, void* d_ws, size_t ws_size,
                              hipStream_t stream)
{
    const float* hidden = (const float*)d_in[0];
    const float* emb    = (const float*)d_in[1];
    const float* hW1    = (const float*)d_in[2];
    const float* hb1    = (const float*)d_in[3];
    const float* hW2    = (const float*)d_in[4];
    const float* hb2    = (const float*)d_in[5];
    const float* tW1    = (const float*)d_in[6];
    const float* tb1    = (const float*)d_in[7];
    const float* tW2    = (const float*)d_in[8];
    const float* tb2    = (const float*)d_in[9];
    const float* bil    = (const float*)d_in[10];
    const float* lW     = (const float*)d_in[11];
    const float* lb     = (const float*)d_in[12];
    const int* ent_start = (const int*)d_in[13];
    const int* ent_label = (const int*)d_in[14];
    const int* rel_head  = (const int*)d_in[15];
    const int* rel_tail  = (const int*)d_in[16];
    const int* rel_label = (const int*)d_in[17];
    float* out = (float*)d_out;

    char* ws = (char*)d_ws;
    ushort_t* repE   = (ushort_t*)(ws + 0);         // [2048,1536]
    ushort_t* hW1T   = (ushort_t*)(ws + 6291456);   // [768,1536]
    ushort_t* tW1T   = (ushort_t*)(ws + 8650752);   // [768,1536]
    ushort_t* hW2T   = (ushort_t*)(ws + 11010048);  // [384,768]
    ushort_t* tW2T   = (ushort_t*)(ws + 11599872);  // [384,768]
    ushort_t* BmatT  = (ushort_t*)(ws + 12189696);  // [770,384]
    ushort_t* lWtT   = (ushort_t*)(ws + 12781056);  // [2,384]
    ushort_t* h1     = (ushort_t*)(ws + 12782592);  // [2048,768]
    ushort_t* t1     = (ushort_t*)(ws + 15928320);  // [2048,768]
    ushort_t* headsE = (ushort_t*)(ws + 19074048);  // [2048,384]
    ushort_t* tailsE = (ushort_t*)(ws + 20646912);  // [2048,384]
    ushort_t* Uext   = (ushort_t*)(ws + 22219776);  // [2048,770]

    prep_kernel<<<3078, 256, 0, stream>>>(
        hidden, emb, lW, ent_start, ent_label, repE, BmatT, lWtT, out);

    transpose_w<<<dim3(48, 24, 6), 256, 0, stream>>>(
        hW1, tW1, hW2, tW2, bil, hW1T, tW1T, hW2T, tW2T, BmatT);

    gemm_lds<<<dim3(16, 6, 2), 256, 0, stream>>>(
        repE, repE, hW1T, tW1T, hb1, tb1, h1, t1, 2048, 768, 1536, 1);

    gemm_lds<<<dim3(16, 3, 2), 256, 0, stream>>>(
        h1, t1, hW2T, tW2T, hb2, tb2, headsE, tailsE, 2048, 384, 768, 1);

    gemm_lds<<<dim3(16, 7, 1), 256, 0, stream>>>(
        headsE, headsE, BmatT, BmatT, nullptr, nullptr, Uext, Uext, 2048, 770, 384, 0);

    rel_kernel<<<1024, 256, 0, stream>>>(
        Uext, tailsE, lWtT, lb, rel_head, rel_tail, rel_label, out);
}

// Round 3
// 180.270 us; speedup vs baseline: 1.3971x; 1.1624x over previous
//
#include <hip/hip_runtime.h>
#include <hip/hip_bf16.h>
#include <cstdint>

typedef unsigned short ushort_t;
typedef __bf16 bf16x8 __attribute__((ext_vector_type(8)));
typedef float f32x4 __attribute__((ext_vector_type(4)));

#define B_   16
#define S_   512
#define D_   768
#define E_   128
#define R_   2048
#define NREL 32768

__device__ inline ushort_t f2b(float f) {
    uint32_t u = __builtin_bit_cast(uint32_t, f);
    uint32_t r = (u + 0x7fffu + ((u >> 16) & 1u)) >> 16;   // RNE
    return (ushort_t)r;
}
__device__ inline float b2f(ushort_t u) {
    uint32_t v = ((uint32_t)u) << 16;
    return __builtin_bit_cast(float, v);
}
__device__ inline float bl(uint32_t u) {
    uint32_t v = u << 16;
    return __builtin_bit_cast(float, v);
}
__device__ inline float bh(uint32_t u) {
    uint32_t v = u & 0xffff0000u;
    return __builtin_bit_cast(float, v);
}

// ---------------------------------------------------------------------------
// Prep: coalesced float4 gather of entity reps -> bf16, plus tiny tails
// (BmatT rows 768/769 from lW-head, lWtT, loss-slot zero).
// ---------------------------------------------------------------------------
__global__ __launch_bounds__(256) void prep_kernel(
    const float* __restrict__ hidden, const float* __restrict__ emb,
    const float* __restrict__ lW,
    const int* __restrict__ ent_start, const int* __restrict__ ent_label,
    ushort_t* __restrict__ repE, ushort_t* __restrict__ BmatT,
    ushort_t* __restrict__ lWtT, float* __restrict__ out)
{
    int idx = blockIdx.x * 256 + threadIdx.x;
    if (idx == 0) out[0] = 0.0f;
    if (idx < 786432) {                      // repE [2048,1536] via float4
        int row = idx / 384, q = idx - row * 384;
        int c = q * 4;
        int b = row >> 7;
        int st = ent_start[row], lab = ent_label[row];
        const float* srcp = (c < 768)
            ? hidden + ((size_t)(b * S_ + st) * D_ + c)
            : emb + ((size_t)lab * D_ + (c - 768));
        float4 v = *reinterpret_cast<const float4*>(srcp);
        uint32_t lo = (uint32_t)f2b(v.x) | ((uint32_t)f2b(v.y) << 16);
        uint32_t hi = (uint32_t)f2b(v.z) | ((uint32_t)f2b(v.w) << 16);
        uint2 pk; pk.x = lo; pk.y = hi;
        *reinterpret_cast<uint2*>(repE + (size_t)idx * 4) = pk;
        return;
    }
    int i2 = idx - 786432;
    if (i2 < 768) {                          // BmatT rows 768/769 (head-linear)
        int o = i2 / 384, kk = i2 - o * 384;
        BmatT[(768 + o) * 384 + kk] = f2b(lW[kk * 2 + o]);
        return;
    }
    i2 -= 768;
    if (i2 < 768) {                          // lWtT [2,384] (tail-linear)
        int o = i2 / 384, ii = i2 - o * 384;
        lWtT[o * 384 + ii] = f2b(lW[(384 + ii) * 2 + o]);
    }
}

// ---------------------------------------------------------------------------
// Coalesced 32x32 LDS-tile transpose fp32 -> bf16, z selects matrix.
// ---------------------------------------------------------------------------
__global__ __launch_bounds__(256) void transpose_w(
    const float* __restrict__ hW1, const float* __restrict__ tW1,
    const float* __restrict__ hW2, const float* __restrict__ tW2,
    const float* __restrict__ bil,
    ushort_t* __restrict__ hW1T, ushort_t* __restrict__ tW1T,
    ushort_t* __restrict__ hW2T, ushort_t* __restrict__ tW2T,
    ushort_t* __restrict__ BmatT)
{
    __shared__ float tile[32][33];
    int z = blockIdx.z;
    const float* src; ushort_t* dst; int Rr, Cc;
    switch (z) {
        case 0:  src = hW1;          dst = hW1T;           Rr = 1536; Cc = 768; break;
        case 1:  src = tW1;          dst = tW1T;           Rr = 1536; Cc = 768; break;
        case 2:  src = hW2;          dst = hW2T;           Rr = 768;  Cc = 384; break;
        case 3:  src = tW2;          dst = tW2T;           Rr = 768;  Cc = 384; break;
        case 4:  src = bil;          dst = BmatT;          Rr = 384;  Cc = 384; break;
        default: src = bil + 147456; dst = BmatT + 147456; Rr = 384;  Cc = 384; break;
    }
    int tR = blockIdx.x * 32, tC = blockIdx.y * 32;
    if (tR >= Rr || tC >= Cc) return;
    int tx = threadIdx.x & 31, ty = threadIdx.x >> 5;     // ty in [0,8)
#pragma unroll
    for (int r = 0; r < 4; ++r)
        tile[ty + r * 8][tx] = src[(size_t)(tR + ty + r * 8) * Cc + tC + tx];
    __syncthreads();
#pragma unroll
    for (int r = 0; r < 4; ++r)
        dst[(size_t)(tC + ty + r * 8) * Rr + tR + tx] = f2b(tile[tx][ty + r * 8]);
}

// ---------------------------------------------------------------------------
// LDS-staged bf16 MFMA GEMM, 64x64 block tile (wave tile 32x32, BK=32).
// Small tiles on purpose: grids of 384-768 blocks give ~3 blocks/CU so other
// blocks' waves hide the vmcnt(0)+barrier drain (1 block/CU exposed it).
// A [M,K] row-major, Bt [N,K] row-major. blockIdx.z selects operand set.
// ---------------------------------------------------------------------------
__global__ __launch_bounds__(256) void gemm_lds(
    const ushort_t* __restrict__ A0, const ushort_t* __restrict__ A1,
    const ushort_t* __restrict__ Bt0, const ushort_t* __restrict__ Bt1,
    const float* __restrict__ bias0, const float* __restrict__ bias1,
    ushort_t* __restrict__ out0, ushort_t* __restrict__ out1,
    int M, int N, int K, int doRelu)
{
    __shared__ ushort_t As[64 * 32];
    __shared__ ushort_t Bs[64 * 32];
    const ushort_t* A   = blockIdx.z ? A1 : A0;
    const ushort_t* Bt  = blockIdx.z ? Bt1 : Bt0;
    const float*   bias = blockIdx.z ? bias1 : bias0;
    ushort_t*      out  = blockIdx.z ? out1 : out0;

    int t = threadIdx.x;
    int lane = t & 63, wave = t >> 6;
    int tileM = blockIdx.x * 64, tileN = blockIdx.y * 64;
    int wm = (wave >> 1) * 32, wn = (wave & 1) * 32;
    int l15 = lane & 15, quad = lane >> 4;

    const ushort_t* gA = A  + (size_t)tileM * K;
    const ushort_t* gB = Bt + (size_t)tileN * K;

    // staging coords: 64 rows x 32 cols = 256 segments of 16B, one per thread
    int srow = t >> 2, sc8 = (t & 3) << 3;

    f32x4 acc[2][2];
#pragma unroll
    for (int a = 0; a < 2; ++a)
#pragma unroll
        for (int b = 0; b < 2; ++b) {
            acc[a][b][0] = 0.f; acc[a][b][1] = 0.f;
            acc[a][b][2] = 0.f; acc[a][b][3] = 0.f;
        }

    for (int k0 = 0; k0 < K; k0 += 32) {
        __builtin_amdgcn_global_load_lds(
            (const __attribute__((address_space(1))) void*)(gA + (size_t)srow * K + k0 + sc8),
            (__attribute__((address_space(3))) void*)(As + t * 8), 16, 0, 0);
        __builtin_amdgcn_global_load_lds(
            (const __attribute__((address_space(1))) void*)(gB + (size_t)srow * K + k0 + sc8),
            (__attribute__((address_space(3))) void*)(Bs + t * 8), 16, 0, 0);
        __syncthreads();
        bf16x8 af[2], bfr[2];
#pragma unroll
        for (int mi = 0; mi < 2; ++mi)
            af[mi] = *reinterpret_cast<const bf16x8*>(As + (wm + mi * 16 + l15) * 32 + quad * 8);
#pragma unroll
        for (int ni = 0; ni < 2; ++ni)
            bfr[ni] = *reinterpret_cast<const bf16x8*>(Bs + (wn + ni * 16 + l15) * 32 + quad * 8);
#pragma unroll
        for (int mi = 0; mi < 2; ++mi)
#pragma unroll
            for (int ni = 0; ni < 2; ++ni)
                acc[mi][ni] = __builtin_amdgcn_mfma_f32_16x16x32_bf16(af[mi], bfr[ni], acc[mi][ni], 0, 0, 0);
        __syncthreads();
    }

#pragma unroll
    for (int mi = 0; mi < 2; ++mi) {
        int gr = tileM + wm + mi * 16 + quad * 4;
#pragma unroll
        for (int ni = 0; ni < 2; ++ni) {
            int gc = tileN + wn + ni * 16 + l15;
            if (gc < N) {
                float bb = bias ? bias[gc] : 0.0f;
#pragma unroll
                for (int r = 0; r < 4; ++r) {
                    float v = acc[mi][ni][r] + bb;
                    if (doRelu) v = fmaxf(v, 0.0f);
                    out[(size_t)(gr + r) * N + gc] = f2b(v);
                }
            }
        }
    }
}

// ---------------------------------------------------------------------------
// Per-relation: logits + log-softmax + loss. One wave per 8 relations.
// ---------------------------------------------------------------------------
__global__ __launch_bounds__(256) void rel_kernel(
    const ushort_t* __restrict__ Uext, const ushort_t* __restrict__ tailsE,
    const ushort_t* __restrict__ lWtT, const float* __restrict__ lb,
    const int* __restrict__ rel_head, const int* __restrict__ rel_tail,
    const int* __restrict__ rel_label, float* __restrict__ out)
{
    __shared__ float wsum[4];
    int lane = threadIdx.x & 63, wave = threadIdx.x >> 6;
    const uint32_t* lw32 = reinterpret_cast<const uint32_t*>(lWtT);
    float lb0 = lb[0], lb1 = lb[1];
    float lossAcc = 0.0f;
    int base = (blockIdx.x * 4 + wave) * 8;

    for (int q = 0; q < 8; ++q) {
        int rel = base + q;
        int b = rel >> 11;                    // R = 2048
        int h = rel_head[rel], t = rel_tail[rel], lab = rel_label[rel];
        const uint32_t* uh = reinterpret_cast<const uint32_t*>(Uext + (size_t)(b * E_ + h) * 770);
        const uint32_t* tv = reinterpret_cast<const uint32_t*>(tailsE + (size_t)(b * E_ + t) * 384);

        float a0 = 0.f, a1 = 0.f, w0s = 0.f, w1s = 0.f;
#pragma unroll
        for (int j = 0; j < 3; ++j) {
            int i = lane + 64 * j;
            uint32_t tu = tv[i];
            uint32_t u0 = uh[i], u1 = uh[192 + i];
            uint32_t q0 = lw32[i], q1 = lw32[192 + i];
            float tl = bl(tu), th = bh(tu);
            a0  += tl * bl(u0) + th * bh(u0);
            a1  += tl * bl(u1) + th * bh(u1);
            w0s += tl * bl(q0) + th * bh(q0);
            w1s += tl * bl(q1) + th * bh(q1);
        }
#pragma unroll
        for (int d = 1; d < 64; d <<= 1) {
            a0  += __shfl_xor(a0, d);
            a1  += __shfl_xor(a1, d);
            w0s += __shfl_xor(w0s, d);
            w1s += __shfl_xor(w1s, d);
        }
        const ushort_t* uhs = reinterpret_cast<const ushort_t*>(uh);
        float l0v = a0 + w0s + b2f(uhs[768]) + lb0;
        float l1v = a1 + w1s + b2f(uhs[769]) + lb1;
        if (lane == 0) {
            out[1 + 2 * rel]     = l0v;
            out[1 + 2 * rel + 1] = l1v;
        }
        float m = fmaxf(l0v, l1v);
        float lse = m + logf(expf(l0v - m) + expf(l1v - m));
        lossAcc += lse - (lab ? l1v : l0v);
    }
    if (lane == 0) wsum[wave] = lossAcc;
    __syncthreads();
    if (threadIdx.x == 0) {
        float s = wsum[0] + wsum[1] + wsum[2] + wsum[3];
        atomicAdd(out, s * (1.0f / 32768.0f));
    }
}

// ---------------------------------------------------------------------------
extern "C" void kernel_launch(void* const* d_in, const int* in_sizes, int n_in,
                              void* d_out, int out_size, void* d_ws, size_t ws_size,
                              hipStream_t stream)
{
    const float* hidden = (const float*)d_in[0];
    const float* emb    = (const float*)d_in[1];
    const float* hW1    = (const float*)d_in[2];
    const float* hb1    = (const float*)d_in[3];
    const float* hW2    = (const float*)d_in[4];
    const float* hb2    = (const float*)d_in[5];
    const float* tW1    = (const float*)d_in[6];
    const float* tb1    = (const float*)d_in[7];
    const float* tW2    = (const float*)d_in[8];
    const float* tb2    = (const float*)d_in[9];
    const float* bil    = (const float*)d_in[10];
    const float* lW     = (const float*)d_in[11];
    const float* lb     = (const float*)d_in[12];
    const int* ent_start = (const int*)d_in[13];
    const int* ent_label = (const int*)d_in[14];
    const int* rel_head  = (const int*)d_in[15];
    const int* rel_tail  = (const int*)d_in[16];
    const int* rel_label = (const int*)d_in[17];
    float* out = (float*)d_out;

    char* ws = (char*)d_ws;
    ushort_t* repE   = (ushort_t*)(ws + 0);         // [2048,1536]
    ushort_t* hW1T   = (ushort_t*)(ws + 6291456);   // [768,1536]
    ushort_t* tW1T   = (ushort_t*)(ws + 8650752);   // [768,1536]
    ushort_t* hW2T   = (ushort_t*)(ws + 11010048);  // [384,768]
    ushort_t* tW2T   = (ushort_t*)(ws + 11599872);  // [384,768]
    ushort_t* BmatT  = (ushort_t*)(ws + 12189696);  // [770,384]
    ushort_t* lWtT   = (ushort_t*)(ws + 12781056);  // [2,384]
    ushort_t* h1     = (ushort_t*)(ws + 12782592);  // [2048,768]
    ushort_t* t1     = (ushort_t*)(ws + 15928320);  // [2048,768]
    ushort_t* headsE = (ushort_t*)(ws + 19074048);  // [2048,384]
    ushort_t* tailsE = (ushort_t*)(ws + 20646912);  // [2048,384]
    ushort_t* Uext   = (ushort_t*)(ws + 22219776);  // [2048,770]

    prep_kernel<<<3078, 256, 0, stream>>>(
        hidden, emb, lW, ent_start, ent_label, repE, BmatT, lWtT, out);

    transpose_w<<<dim3(48, 24, 6), 256, 0, stream>>>(
        hW1, tW1, hW2, tW2, bil, hW1T, tW1T, hW2T, tW2T, BmatT);

    gemm_lds<<<dim3(32, 12, 2), 256, 0, stream>>>(
        repE, repE, hW1T, tW1T, hb1, tb1, h1, t1, 2048, 768, 1536, 1);

    gemm_lds<<<dim3(32, 6, 2), 256, 0, stream>>>(
        h1, t1, hW2T, tW2T, hb2, tb2, headsE, tailsE, 2048, 384, 768, 1);

    gemm_lds<<<dim3(32, 13, 1), 256, 0, stream>>>(
        headsE, headsE, BmatT, BmatT, nullptr, nullptr, Uext, Uext, 2048, 770, 384, 0);

    rel_kernel<<<1024, 256, 0, stream>>>(
        Uext, tailsE, lWtT, lb, rel_head, rel_tail, rel_label, out);
}